// Round 4
// baseline (457.231 us; speedup 1.0000x reference)
//
#include <hip/hip_runtime.h>
#include <hip/hip_cooperative_groups.h>
#include <math.h>

#define B_ 64
#define N_ 16384
#define M_ 64

namespace cg = cooperative_groups;

// Native clang vector type — required by __builtin_nontemporal_load.
typedef float vfloat4 __attribute__((ext_vector_type(4)));

// Single fused cooperative kernel. 256 blocks x 1024 threads (1 block/CU,
// 16 waves/CU). Block blk: batch b = blk>>2, quarter q = blk&3 owns rows
// [q*4096, q*4096+4096) of that batch.
//   Phase 1: exp-scores (4 lanes/row, DPP quad reduce, nontemporal streaming
//            of the 256 MB memory tensor) -> LDS sc[4096]; per-block partial
//            softmax denominator -> ws (agent-scope atomic store).
//   grid.sync()
//   Phase 2: Z from 4 partials; gate with last_address; circular 3-tap shift
//            (intra-block via LDS, block edges via ws boundary scores);
//            sharpen; per-block partial sum -> ws.
//   grid.sync()
//   Normalize + coalesced float4 store.
__global__ __launch_bounds__(1024, 4) void ntm_fused(
    const float* __restrict__ key, const float* __restrict__ beta,
    const float* __restrict__ gate, const float* __restrict__ shift,
    const float* __restrict__ sharpen, const float* __restrict__ la,
    const float* __restrict__ memory, float* __restrict__ out,
    float* __restrict__ wsp)
{
    const int blk  = blockIdx.x;     // 0..255
    const int b    = blk >> 2;
    const int q    = blk & 3;
    const int R0   = q << 12;        // q*4096
    const int t    = threadIdx.x;    // 0..1023
    const int lane = t & 63;
    const int w    = t >> 6;         // wave 0..15
    const int l    = lane & 3;       // 16B chunk within 64B row-quarter
    const int rr   = lane >> 2;      // row within group of 16

    __shared__ float sc[4096];       // exp-scores for this block's rows (16 KB)
    __shared__ float wred[16];
    __shared__ float bx[8];          // broadcast: partials / boundary scores
    __shared__ float lft[1024], rgt[1024];

    float* zpart = wsp;              // [256] partial softmax denominators
    float* spart = wsp + 256;        // [256] partial sharpened sums
    float* bsc   = wsp + 512;        // [256][2] first/last exp-score per block

    // ---------------- Phase 1: exp-scores ----------------
    vfloat4 k4[4];
#pragma unroll
    for (int j = 0; j < 4; ++j)
        k4[j] = *reinterpret_cast<const vfloat4*>(key + b * M_ + j * 16 + l * 4);
    float ksq = 0.f;
#pragma unroll
    for (int j = 0; j < 4; ++j)
        ksq += k4[j].x * k4[j].x + k4[j].y * k4[j].y + k4[j].z * k4[j].z + k4[j].w * k4[j].w;
    ksq += __shfl_xor(ksq, 1);   // DPP quad_perm
    ksq += __shfl_xor(ksq, 2);
    const float knorm = sqrtf(ksq);
    const float kb    = beta[b];

    const float* __restrict__ mb = memory + ((size_t)b * N_ + R0) * M_;

    float zs = 0.f;
    const int waveBase = w << 8;     // wave owns 256 rows
#pragma unroll 4
    for (int it = 0; it < 16; ++it) {
        const int lr = waveBase + (it << 4) + rr;
        const float* rp = mb + (size_t)lr * M_;
        vfloat4 m4[4];
#pragma unroll
        for (int j = 0; j < 4; ++j)
            m4[j] = __builtin_nontemporal_load(
                reinterpret_cast<const vfloat4*>(rp + j * 16 + l * 4));
        float dot = 0.f, msq = 0.f;
#pragma unroll
        for (int j = 0; j < 4; ++j) {
            dot += k4[j].x * m4[j].x + k4[j].y * m4[j].y + k4[j].z * m4[j].z + k4[j].w * m4[j].w;
            msq += m4[j].x * m4[j].x + m4[j].y * m4[j].y + m4[j].z * m4[j].z + m4[j].w * m4[j].w;
        }
        dot += __shfl_xor(dot, 1); dot += __shfl_xor(dot, 2);
        msq += __shfl_xor(msq, 1); msq += __shfl_xor(msq, 2);
        // all 4 quad lanes hold full sums -> all compute e (each row counted 4x in zs)
        const float e = expf(kb * dot / fmaxf(knorm * sqrtf(msq), 1e-8f));
        if (l == 0) sc[lr] = e;
        zs += e;
    }
#pragma unroll
    for (int m = 1; m < 64; m <<= 1) zs += __shfl_xor(zs, m);
    if (lane == 0) wred[w] = zs * 0.25f;   // undo 4x quad duplication
    __syncthreads();
    if (t == 0) {
        float pz = 0.f;
#pragma unroll
        for (int i = 0; i < 16; ++i) pz += wred[i];
        __hip_atomic_store(&zpart[blk], pz, __ATOMIC_RELEASE, __HIP_MEMORY_SCOPE_AGENT);
        __hip_atomic_store(&bsc[blk * 2 + 0], sc[0],    __ATOMIC_RELEASE, __HIP_MEMORY_SCOPE_AGENT);
        __hip_atomic_store(&bsc[blk * 2 + 1], sc[4095], __ATOMIC_RELEASE, __HIP_MEMORY_SCOPE_AGENT);
    }
    cg::this_grid().sync();

    // ---------------- Phase 2: gate + shift + sharpen ----------------
    if (t < 4)
        bx[t] = __hip_atomic_load(&zpart[b * 4 + t], __ATOMIC_ACQUIRE, __HIP_MEMORY_SCOPE_AGENT);
    if (t == 4) {
        const int pblk = b * 4 + ((q + 3) & 3);   // owner of row R0-1 (circular)
        bx[4] = __hip_atomic_load(&bsc[pblk * 2 + 1], __ATOMIC_ACQUIRE, __HIP_MEMORY_SCOPE_AGENT);
    }
    if (t == 5) {
        const int nblk = b * 4 + ((q + 1) & 3);   // owner of row R0+4096 (circular)
        bx[5] = __hip_atomic_load(&bsc[nblk * 2 + 0], __ATOMIC_ACQUIRE, __HIP_MEMORY_SCOPE_AGENT);
    }
    __syncthreads();
    const float invZ = 1.0f / (bx[0] + bx[1] + bx[2] + bx[3]);
    const float gg = gate[b], om = 1.0f - gg;
    const float s0 = shift[b * 3 + 0], s1 = shift[b * 3 + 1], s2 = shift[b * 3 + 2];

    // thread t owns 4 consecutive rows R0 + t*4 .. +3
    const float4 sv = *reinterpret_cast<const float4*>(sc + t * 4);
    const float4 lv = *reinterpret_cast<const float4*>(la + (size_t)b * N_ + R0 + t * 4);
    const float wg0 = gg * (sv.x * invZ) + om * lv.x;
    const float wg1 = gg * (sv.y * invZ) + om * lv.y;
    const float wg2 = gg * (sv.z * invZ) + om * lv.z;
    const float wg3 = gg * (sv.w * invZ) + om * lv.w;

    lft[t] = wg0; rgt[t] = wg3;
    __syncthreads();
    float prev, nxt;
    if (t == 0) {
        const int pr = (R0 - 1) & (N_ - 1);
        prev = gg * (bx[4] * invZ) + om * la[(size_t)b * N_ + pr];
    } else prev = rgt[t - 1];
    if (t == 1023) {
        const int nr = (R0 + 4096) & (N_ - 1);
        nxt = gg * (bx[5] * invZ) + om * la[(size_t)b * N_ + nr];
    } else nxt = lft[t + 1];

    float w0 = s0 * prev + s1 * wg0 + s2 * wg1;
    float w1 = s0 * wg0  + s1 * wg1 + s2 * wg2;
    float w2 = s0 * wg1  + s1 * wg2 + s2 * wg3;
    float w3 = s0 * wg2  + s1 * wg3 + s2 * nxt;

    // sharpen: x^p = exp2(p*log2 x); x>=0, log2(0)=-inf -> exp2 -> 0 (correct)
    const float p = sharpen[b];
    w0 = exp2f(p * log2f(w0));
    w1 = exp2f(p * log2f(w1));
    w2 = exp2f(p * log2f(w2));
    w3 = exp2f(p * log2f(w3));
    float ss = w0 + w1 + w2 + w3;
#pragma unroll
    for (int m = 1; m < 64; m <<= 1) ss += __shfl_xor(ss, m);
    if (lane == 0) wred[w] = ss;
    __syncthreads();
    if (t == 0) {
        float ps = 0.f;
#pragma unroll
        for (int i = 0; i < 16; ++i) ps += wred[i];
        __hip_atomic_store(&spart[blk], ps, __ATOMIC_RELEASE, __HIP_MEMORY_SCOPE_AGENT);
    }
    cg::this_grid().sync();

    // ---------------- Normalize + store ----------------
    if (t < 4)
        bx[t] = __hip_atomic_load(&spart[b * 4 + t], __ATOMIC_ACQUIRE, __HIP_MEMORY_SCOPE_AGENT);
    __syncthreads();
    const float inv = 1.0f / (bx[0] + bx[1] + bx[2] + bx[3] + 1e-16f);
    float4 o;
    o.x = w0 * inv; o.y = w1 * inv; o.z = w2 * inv; o.w = w3 * inv;
    *reinterpret_cast<float4*>(out + (size_t)b * N_ + R0 + t * 4) = o;
}

extern "C" void kernel_launch(void* const* d_in, const int* in_sizes, int n_in,
                              void* d_out, int out_size, void* d_ws, size_t ws_size,
                              hipStream_t stream) {
    const float* key     = (const float*)d_in[0];  // [B, M]
    const float* beta    = (const float*)d_in[1];  // [B, 1]
    const float* gate    = (const float*)d_in[2];  // [B, 1]
    const float* shift   = (const float*)d_in[3];  // [B, 3]
    const float* sharpen = (const float*)d_in[4];  // [B, 1]
    const float* la      = (const float*)d_in[5];  // [B, N]
    const float* memory  = (const float*)d_in[6];  // [B, N, M]
    float* out = (float*)d_out;                    // [B, N]
    float* wsf = (float*)d_ws;                     // 1024 floats used

    void* args[] = { (void*)&key, (void*)&beta, (void*)&gate, (void*)&shift,
                     (void*)&sharpen, (void*)&la, (void*)&memory,
                     (void*)&out, (void*)&wsf };
    hipLaunchCooperativeKernel((const void*)ntm_fused, dim3(256), dim3(1024),
                               args, 0, stream);
}

// Round 5
// 378.113 us; speedup vs baseline: 1.2092x; 1.2092x over previous
//
#include <hip/hip_runtime.h>
#include <math.h>

#define B_ 64
#define N_ 16384
#define M_ 64

// Native clang vector type (bit-identical to float4, works with vector ops).
typedef float vfloat4 __attribute__((ext_vector_type(4)));

// ---------------- Pass A: s[b,n] = exp(beta_b * cos(key_b, memory[b,n,:])) ----------------
// grid = (N/256, B), block = 256 (4 waves). Layout: 4 lanes per row, each lane loads
// 4x float4 (one 64B row-quarter per lane-load -> every 64B segment fully covered).
// Cross-lane reduction is quad-local: __shfl_xor(1/2) -> DPP quad_perm, zero DS-pipe.
// |beta*cos| <= 5 so exp() is overflow-safe without max subtraction -> folded here.
// R5 changes vs R3: plain loads (NT removed — m13's 6.29 TB/s ceiling used plain loads)
// and an explicit 2-stage software pipeline (iter t+1 loads issued before iter t math).
__global__ __launch_bounds__(256) void scores_kernel(
    const float* __restrict__ key, const float* __restrict__ beta,
    const float* __restrict__ memory, float* __restrict__ s_out)
{
    const int b    = blockIdx.y;
    const int tid  = threadIdx.x;
    const int lane = tid & 63;
    const int wave = tid >> 6;    // 0..3
    const int l    = lane & 3;    // 16B chunk within a 64B row-quarter
    const int rr   = lane >> 2;   // row within group of 16

    // per-lane key fragments: k4[j] = key[b, j*16 + l*4 .. +4]
    vfloat4 k4[4];
#pragma unroll
    for (int j = 0; j < 4; ++j)
        k4[j] = *reinterpret_cast<const vfloat4*>(key + b * M_ + j * 16 + l * 4);

    float ksq = 0.f;
#pragma unroll
    for (int j = 0; j < 4; ++j)
        ksq += k4[j].x * k4[j].x + k4[j].y * k4[j].y + k4[j].z * k4[j].z + k4[j].w * k4[j].w;
    ksq += __shfl_xor(ksq, 1);   // DPP quad_perm
    ksq += __shfl_xor(ksq, 2);
    const float knorm = sqrtf(ksq);
    const float kb    = beta[b];

    const float* __restrict__ mb = memory + (size_t)b * N_ * M_;
    float* __restrict__ sb       = s_out + (size_t)b * N_;

    const int rowBase = blockIdx.x * 256 + wave * 64;   // this wave owns 64 rows
    // lane's base pointer for iteration 0 (row rowBase+rr, chunk l)
    const float* rp0 = mb + (size_t)(rowBase + rr) * M_ + l * 4;

    // ---- explicit 2-stage pipeline: loads of iter t+1 in flight during iter t math ----
    vfloat4 cur[4], nxt[4];
#pragma unroll
    for (int j = 0; j < 4; ++j)
        cur[j] = *reinterpret_cast<const vfloat4*>(rp0 + j * 16);

#pragma unroll
    for (int t = 0; t < 4; ++t) {                 // 16 rows (4 KB/wave) per iter
        if (t < 3) {
            const float* rpn = rp0 + (size_t)(t + 1) * (16 * M_);
#pragma unroll
            for (int j = 0; j < 4; ++j)
                nxt[j] = *reinterpret_cast<const vfloat4*>(rpn + j * 16);
        }

        float dot = 0.f, msq = 0.f;
#pragma unroll
        for (int j = 0; j < 4; ++j) {
            dot += k4[j].x * cur[j].x + k4[j].y * cur[j].y + k4[j].z * cur[j].z + k4[j].w * cur[j].w;
            msq += cur[j].x * cur[j].x + cur[j].y * cur[j].y + cur[j].z * cur[j].z + cur[j].w * cur[j].w;
        }
        dot += __shfl_xor(dot, 1);  dot += __shfl_xor(dot, 2);   // DPP quad reduce
        msq += __shfl_xor(msq, 1);  msq += __shfl_xor(msq, 2);

        if (l == 0) {
            const float denom = fmaxf(knorm * sqrtf(msq), 1e-8f);
            sb[rowBase + t * 16 + rr] = expf(kb * dot / denom);
        }

#pragma unroll
        for (int j = 0; j < 4; ++j) cur[j] = nxt[j];   // renamed away by regalloc
    }
}

// ---------------- Pass B: softmax-denominator + gate + circular shift + sharpen + renorm ----
// One block (1024 threads) per batch; each thread owns 16 contiguous elements in registers.
// Scores arrive already exponentiated -> only a sum reduction is needed for softmax.
// (Byte-identical to R3 — isolates this round's delta to scores_kernel.)
__global__ __launch_bounds__(1024) void addr_kernel(
    const float* __restrict__ gate, const float* __restrict__ shift,
    const float* __restrict__ sharpen, const float* __restrict__ la,
    float* __restrict__ out)
{
    const int b    = blockIdx.x;
    const int t    = threadIdx.x;   // 0..1023
    const int lane = t & 63;
    const int wv   = t >> 6;        // 0..15

    __shared__ float red[16];
    __shared__ float lft[1024];
    __shared__ float rgt[1024];

    float* __restrict__ ob        = out + (size_t)b * N_;
    const float* __restrict__ lab = la + (size_t)b * N_;

    // load exp-scores (this batch's slice of d_out) into registers
    float s[16];
#pragma unroll
    for (int q = 0; q < 4; ++q)
        *reinterpret_cast<float4*>(&s[4 * q]) =
            reinterpret_cast<const float4*>(ob)[t * 4 + q];

    // ---- block sum -> softmax denominator ----
    float zs = 0.f;
#pragma unroll
    for (int i = 0; i < 16; ++i) zs += s[i];
#pragma unroll
    for (int m = 1; m < 64; m <<= 1) zs += __shfl_xor(zs, m);
    if (lane == 0) red[wv] = zs;
    __syncthreads();
    float Z = red[0];
#pragma unroll
    for (int i = 1; i < 16; ++i) Z += red[i];
    __syncthreads();
    const float invZ = 1.0f / Z;

    // ---- gate interpolation ----
    const float gg = gate[b];
    const float om = 1.0f - gg;
    float wl[16];
#pragma unroll
    for (int q = 0; q < 4; ++q)
        *reinterpret_cast<float4*>(&wl[4 * q]) =
            reinterpret_cast<const float4*>(lab)[t * 4 + q];
    float wg[16];
#pragma unroll
    for (int i = 0; i < 16; ++i) wg[i] = gg * (s[i] * invZ) + om * wl[i];

    // ---- circular 3-tap shift: boundary exchange via LDS ----
    lft[t] = wg[0];
    rgt[t] = wg[15];
    __syncthreads();
    const float prev = rgt[(t + 1023) & 1023];
    const float nxt  = lft[(t + 1) & 1023];
    const float s0 = shift[b * 3 + 0];
    const float s1 = shift[b * 3 + 1];
    const float s2 = shift[b * 3 + 2];
    float ws[16];
    ws[0] = s0 * prev + s1 * wg[0] + s2 * wg[1];
#pragma unroll
    for (int i = 1; i < 15; ++i) ws[i] = s0 * wg[i - 1] + s1 * wg[i] + s2 * wg[i + 1];
    ws[15] = s0 * wg[14] + s1 * wg[15] + s2 * nxt;

    // ---- sharpen (x^p = exp2(p*log2 x), valid for x>=0) + block sum + renorm ----
    const float p = sharpen[b];
    float ssum = 0.f;
#pragma unroll
    for (int i = 0; i < 16; ++i) { ws[i] = exp2f(p * log2f(ws[i])); ssum += ws[i]; }
#pragma unroll
    for (int m = 1; m < 64; m <<= 1) ssum += __shfl_xor(ssum, m);
    __syncthreads();   // red reuse: ensure previous reads done
    if (lane == 0) red[wv] = ssum;
    __syncthreads();
    float S = red[0];
#pragma unroll
    for (int i = 1; i < 16; ++i) S += red[i];
    const float inv = 1.0f / (S + 1e-16f);

#pragma unroll
    for (int q = 0; q < 4; ++q) {
        float4 o;
        o.x = ws[4 * q + 0] * inv;
        o.y = ws[4 * q + 1] * inv;
        o.z = ws[4 * q + 2] * inv;
        o.w = ws[4 * q + 3] * inv;
        reinterpret_cast<float4*>(ob)[t * 4 + q] = o;
    }
}

extern "C" void kernel_launch(void* const* d_in, const int* in_sizes, int n_in,
                              void* d_out, int out_size, void* d_ws, size_t ws_size,
                              hipStream_t stream) {
    const float* key     = (const float*)d_in[0];  // [B, M]
    const float* beta    = (const float*)d_in[1];  // [B, 1]
    const float* gate    = (const float*)d_in[2];  // [B, 1]
    const float* shift   = (const float*)d_in[3];  // [B, 3]
    const float* sharpen = (const float*)d_in[4];  // [B, 1]
    const float* la      = (const float*)d_in[5];  // [B, N]
    const float* memory  = (const float*)d_in[6];  // [B, N, M]
    float* out = (float*)d_out;                    // [B, N] (also used as exp-score scratch)

    dim3 gridA(N_ / 256, B_);
    scores_kernel<<<gridA, 256, 0, stream>>>(key, beta, memory, out);

    addr_kernel<<<B_, 1024, 0, stream>>>(gate, shift, sharpen, la, out);
}

// Round 6
// 357.600 us; speedup vs baseline: 1.2786x; 1.0574x over previous
//
#include <hip/hip_runtime.h>
#include <math.h>

#define B_ 64
#define N_ 16384
#define M_ 64

// Native clang vector type — required by __builtin_nontemporal_load.
typedef float vfloat4 __attribute__((ext_vector_type(4)));

// ---------------- Pass A: s[b,n] = exp(beta_b * cos(key_b, memory[b,n,:])) ----------------
// grid = (N/256, B), block = 256 (4 waves). 4 lanes per row; each lane loads 4x16B
// covering a 64B row-quarter; quad-local reduction via __shfl_xor(1/2) -> DPP, no DS pipe.
// R6: NT loads restored (R5 removal cost +21us — L2 thrash from the 256MB stream) and
// ALL 16 loads issued up front (16KB/wave in flight -> max MLP, staged vmcnt waits).
__global__ __launch_bounds__(256) void scores_kernel(
    const float* __restrict__ key, const float* __restrict__ beta,
    const float* __restrict__ memory, float* __restrict__ s_out)
{
    const int b    = blockIdx.y;
    const int tid  = threadIdx.x;
    const int lane = tid & 63;
    const int wave = tid >> 6;    // 0..3
    const int l    = lane & 3;    // 16B chunk within a 64B row-quarter
    const int rr   = lane >> 2;   // row within group of 16

    // per-lane key fragments: k4[j] = key[b, j*16 + l*4 .. +4]
    vfloat4 k4[4];
#pragma unroll
    for (int j = 0; j < 4; ++j)
        k4[j] = *reinterpret_cast<const vfloat4*>(key + b * M_ + j * 16 + l * 4);

    float ksq = 0.f;
#pragma unroll
    for (int j = 0; j < 4; ++j)
        ksq += k4[j].x * k4[j].x + k4[j].y * k4[j].y + k4[j].z * k4[j].z + k4[j].w * k4[j].w;
    ksq += __shfl_xor(ksq, 1);   // DPP quad_perm
    ksq += __shfl_xor(ksq, 2);
    const float knorm = sqrtf(ksq);
    const float kb    = beta[b];

    const float* __restrict__ mb = memory + (size_t)b * N_ * M_;
    float* __restrict__ sb       = s_out + (size_t)b * N_;

    const int rowBase = blockIdx.x * 256 + wave * 64;   // this wave owns 64 rows (16 KB)
    const float* rp0  = mb + (size_t)(rowBase + rr) * M_ + l * 4;

    // ---- issue ALL 16 NT loads first: whole wave tile in flight ----
    vfloat4 m4[16];
#pragma unroll
    for (int t = 0; t < 4; ++t)
#pragma unroll
        for (int j = 0; j < 4; ++j)
            m4[t * 4 + j] = __builtin_nontemporal_load(
                reinterpret_cast<const vfloat4*>(rp0 + (size_t)t * (16 * M_) + j * 16));

    // ---- consume in order (compiler emits staged s_waitcnt vmcnt(N)) ----
#pragma unroll
    for (int t = 0; t < 4; ++t) {
        float dot = 0.f, msq = 0.f;
#pragma unroll
        for (int j = 0; j < 4; ++j) {
            const vfloat4 v = m4[t * 4 + j];
            dot += k4[j].x * v.x + k4[j].y * v.y + k4[j].z * v.z + k4[j].w * v.w;
            msq += v.x * v.x + v.y * v.y + v.z * v.z + v.w * v.w;
        }
        dot += __shfl_xor(dot, 1);  dot += __shfl_xor(dot, 2);   // DPP quad reduce
        msq += __shfl_xor(msq, 1);  msq += __shfl_xor(msq, 2);

        if (l == 0) {
            const float denom = fmaxf(knorm * sqrtf(msq), 1e-8f);
            sb[rowBase + t * 16 + rr] = expf(kb * dot / denom);  // 16 consecutive floats
        }
    }
}

// ---------------- Pass B: softmax-denominator + gate + circular shift + sharpen + renorm ----
// One block (1024 threads) per batch; each thread owns 16 contiguous elements in registers.
// Scores arrive already exponentiated -> only a sum reduction is needed for softmax.
// (Byte-identical since R3 — isolates this round's delta to scores_kernel.)
__global__ __launch_bounds__(1024) void addr_kernel(
    const float* __restrict__ gate, const float* __restrict__ shift,
    const float* __restrict__ sharpen, const float* __restrict__ la,
    float* __restrict__ out)
{
    const int b    = blockIdx.x;
    const int t    = threadIdx.x;   // 0..1023
    const int lane = t & 63;
    const int wv   = t >> 6;        // 0..15

    __shared__ float red[16];
    __shared__ float lft[1024];
    __shared__ float rgt[1024];

    float* __restrict__ ob        = out + (size_t)b * N_;
    const float* __restrict__ lab = la + (size_t)b * N_;

    // load exp-scores (this batch's slice of d_out) into registers
    float s[16];
#pragma unroll
    for (int q = 0; q < 4; ++q)
        *reinterpret_cast<float4*>(&s[4 * q]) =
            reinterpret_cast<const float4*>(ob)[t * 4 + q];

    // ---- block sum -> softmax denominator ----
    float zs = 0.f;
#pragma unroll
    for (int i = 0; i < 16; ++i) zs += s[i];
#pragma unroll
    for (int m = 1; m < 64; m <<= 1) zs += __shfl_xor(zs, m);
    if (lane == 0) red[wv] = zs;
    __syncthreads();
    float Z = red[0];
#pragma unroll
    for (int i = 1; i < 16; ++i) Z += red[i];
    __syncthreads();
    const float invZ = 1.0f / Z;

    // ---- gate interpolation ----
    const float gg = gate[b];
    const float om = 1.0f - gg;
    float wl[16];
#pragma unroll
    for (int q = 0; q < 4; ++q)
        *reinterpret_cast<float4*>(&wl[4 * q]) =
            reinterpret_cast<const float4*>(lab)[t * 4 + q];
    float wg[16];
#pragma unroll
    for (int i = 0; i < 16; ++i) wg[i] = gg * (s[i] * invZ) + om * wl[i];

    // ---- circular 3-tap shift: boundary exchange via LDS ----
    lft[t] = wg[0];
    rgt[t] = wg[15];
    __syncthreads();
    const float prev = rgt[(t + 1023) & 1023];
    const float nxt  = lft[(t + 1) & 1023];
    const float s0 = shift[b * 3 + 0];
    const float s1 = shift[b * 3 + 1];
    const float s2 = shift[b * 3 + 2];
    float ws[16];
    ws[0] = s0 * prev + s1 * wg[0] + s2 * wg[1];
#pragma unroll
    for (int i = 1; i < 15; ++i) ws[i] = s0 * wg[i - 1] + s1 * wg[i] + s2 * wg[i + 1];
    ws[15] = s0 * wg[14] + s1 * wg[15] + s2 * nxt;

    // ---- sharpen (x^p = exp2(p*log2 x), valid for x>=0) + block sum + renorm ----
    const float p = sharpen[b];
    float ssum = 0.f;
#pragma unroll
    for (int i = 0; i < 16; ++i) { ws[i] = exp2f(p * log2f(ws[i])); ssum += ws[i]; }
#pragma unroll
    for (int m = 1; m < 64; m <<= 1) ssum += __shfl_xor(ssum, m);
    __syncthreads();   // red reuse: ensure previous reads done
    if (lane == 0) red[wv] = ssum;
    __syncthreads();
    float S = red[0];
#pragma unroll
    for (int i = 1; i < 16; ++i) S += red[i];
    const float inv = 1.0f / (S + 1e-16f);

#pragma unroll
    for (int q = 0; q < 4; ++q) {
        float4 o;
        o.x = ws[4 * q + 0] * inv;
        o.y = ws[4 * q + 1] * inv;
        o.z = ws[4 * q + 2] * inv;
        o.w = ws[4 * q + 3] * inv;
        reinterpret_cast<float4*>(ob)[t * 4 + q] = o;
    }
}

extern "C" void kernel_launch(void* const* d_in, const int* in_sizes, int n_in,
                              void* d_out, int out_size, void* d_ws, size_t ws_size,
                              hipStream_t stream) {
    const float* key     = (const float*)d_in[0];  // [B, M]
    const float* beta    = (const float*)d_in[1];  // [B, 1]
    const float* gate    = (const float*)d_in[2];  // [B, 1]
    const float* shift   = (const float*)d_in[3];  // [B, 3]
    const float* sharpen = (const float*)d_in[4];  // [B, 1]
    const float* la      = (const float*)d_in[5];  // [B, N]
    const float* memory  = (const float*)d_in[6];  // [B, N, M]
    float* out = (float*)d_out;                    // [B, N] (also used as exp-score scratch)

    dim3 gridA(N_ / 256, B_);
    scores_kernel<<<gridA, 256, 0, stream>>>(key, beta, memory, out);

    addr_kernel<<<B_, 1024, 0, stream>>>(gate, shift, sharpen, la, out);
}